// Round 7
// baseline (595.473 us; speedup 1.0000x reference)
//
#include <hip/hip_runtime.h>

typedef unsigned short u16;
typedef unsigned int u32;
typedef __bf16 bf16x8 __attribute__((ext_vector_type(8)));
typedef float f32x4 __attribute__((ext_vector_type(4)));

#define T_DIM 256
#define U_DIM 64
#define DJ 640
#define VOCAB 1024

typedef __attribute__((address_space(3))) u32 lds_u32;
typedef const __attribute__((address_space(1))) u32 glb_u32;

__device__ __forceinline__ u16 f2bf(float f) {
    u32 x = __float_as_uint(f);
    x += 0x7fffu + ((x >> 16) & 1u);
    return (u16)(x >> 16);
}

__device__ __forceinline__ float fast_tanh(float x) {
    float e = __expf(2.0f * x);
    return 1.0f - 2.0f / (e + 1.0f);
}

// W_out (640x1024 fp32) -> Wt (1024x640 bf16, [n][k]) via 32x32 LDS tile transpose.
__global__ __launch_bounds__(256) void convert_wout(const float* __restrict__ W,
                                                    u16* __restrict__ Wt) {
    __shared__ float tile[32][33];
    int tx = threadIdx.x & 31, ty = threadIdx.x >> 5;
    int n0 = blockIdx.x * 32, k0 = blockIdx.y * 32;
#pragma unroll
    for (int j = 0; j < 4; j++)
        tile[ty + j * 8][tx] = W[(size_t)(k0 + ty + j * 8) * VOCAB + n0 + tx];
    __syncthreads();
#pragma unroll
    for (int j = 0; j < 4; j++)
        Wt[(size_t)(n0 + ty + j * 8) * DJ + k0 + tx] = f2bf(tile[tx][ty + j * 8]);
}

// out[r,j] = bias[j] + sum_k X[r,k]*W[k,j]; 4 rows x 128 cols per block, K compile-time
template <int K>
__global__ __launch_bounds__(128) void proj_kernel(const float* __restrict__ X,
                                                   const float* __restrict__ W,
                                                   const float* __restrict__ bias,
                                                   float* __restrict__ out) {
    __shared__ float xs[4][K];
    int r0 = blockIdx.x * 4;
    int jj = blockIdx.y * 128 + threadIdx.x;
    for (int idx = threadIdx.x; idx < 4 * K; idx += 128) {
        int r = idx / K, k = idx - r * K;
        xs[r][k] = X[(size_t)(r0 + r) * K + k];
    }
    __syncthreads();
    float b = bias[jj];
    float a0 = b, a1 = b, a2 = b, a3 = b;
#pragma unroll 8
    for (int k = 0; k < K; k++) {
        float w = W[(size_t)k * DJ + jj];
        a0 = fmaf(xs[0][k], w, a0);
        a1 = fmaf(xs[1][k], w, a1);
        a2 = fmaf(xs[2][k], w, a2);
        a3 = fmaf(xs[3][k], w, a3);
    }
    out[(size_t)(r0 + 0) * DJ + jj] = a0;
    out[(size_t)(r0 + 1) * DJ + jj] = a1;
    out[(size_t)(r0 + 2) * DJ + jj] = a2;
    out[(size_t)(r0 + 3) * DJ + jj] = a3;
}

// Fused joint GEMM: C[65536x1024] = tanh(enc⊕pred)[65536x640] * Wt[1024x640]^T + bias, clamp.
// 128x128 tile, BK=64, 256 threads. B via global_load_lds (linear dest, pre-swizzled source).
// A computed on the fly: per K-step, 256 threads compute the 128x64 bf16 A-tile from
// enc_proj (2 rows) + pred_proj (64 rows, L2-resident) into the SAME XOR-swizzled LDS
// layout (logical chunk c of row r at slot c^(r&7)) the gload_lds path produced.
// MFMA loop / read swizzle / epilogue identical to the R4-verified kernel.
__global__ __launch_bounds__(256) void fused_gemm(const float* __restrict__ encp,
                                                  const float* __restrict__ predp,
                                                  const u16* __restrict__ Wt,
                                                  const float* __restrict__ b_out,
                                                  float* __restrict__ out) {
    __shared__ u16 As[128 * 64];
    __shared__ u16 Bs[128 * 64];

    // XCD swizzle: 4096 blocks, 8 XCDs, 512 per chunk (bijective since 4096 % 8 == 0).
    int bid = blockIdx.x;
    int swz = (bid & 7) * 512 + (bid >> 3);
    int ntile = swz & 7;
    int mtile = swz >> 3;
    int row0 = mtile * 128;
    int n0 = ntile * 128;

    int tid = threadIdx.x;
    int lane = tid & 63;
    int wave = tid >> 6;
    int wm = wave & 1;
    int wn = wave >> 1;
    int lm = lane & 15;
    int quad = lane >> 4;

    // B staging: inst i covers rows i*32 + wave*8 + (lane>>3), 8 lanes per 128B row.
    int rS = wave * 8 + (lane >> 3);
    int kSwz = ((lane ^ (lane >> 3)) & 7) * 8;          // pre-swizzled global k-chunk
    const u16* gB = Wt + (size_t)(n0 + rS) * DJ + kSwz;
    u16* lB = Bs + wave * 8 * 64;    // wave-uniform base; HW adds lane*16B (linear dest)

    // A-tile source rows: 128-row tile = 2 enc rows (bt0, bt0+1) x 64 pred rows.
    int bt0 = row0 >> 6;             // enc_proj row index base (= b*T + t)
    int bu0 = (row0 >> 14) * 64;     // pred_proj row index base (= b*U)

    // read side: logical chunk (s*4+quad) lives at slot (s*4+quad) ^ (row&7), row&7 == lm&7
    int abase = (wm * 64 + lm) * 64;
    int bbase = (wn * 64 + lm) * 64;
    int c0 = ((quad ^ (lm & 7))) * 8;                   // s = 0
    int c1 = (((quad ^ 4) ^ (lm & 7))) * 8;             // s = 1

    f32x4 acc[4][4];
#pragma unroll
    for (int i = 0; i < 4; i++)
#pragma unroll
        for (int j = 0; j < 4; j++) {
            acc[i][j][0] = 0.f; acc[i][j][1] = 0.f;
            acc[i][j][2] = 0.f; acc[i][j][3] = 0.f;
        }

    for (int k0 = 0; k0 < DJ; k0 += 64) {
        // issue B loads first: HBM/L2 latency hides under the tanh VALU below
#pragma unroll
        for (int i = 0; i < 4; i++)
            __builtin_amdgcn_global_load_lds((glb_u32*)(gB + (size_t)i * 32 * DJ + k0),
                                             (lds_u32*)(lB + i * 32 * 64), 16, 0, 0);

        // A-tile: 1024 chunks (row r 0..127, chunk c 0..7 = 8 bf16); thread does 4 chunks.
#pragma unroll
        for (int j = 0; j < 4; j++) {
            int ch = tid + j * 256;
            int r = ch >> 3;
            int c = ch & 7;
            int k8 = k0 + c * 8;
            const float4* pe = (const float4*)(encp + (size_t)(bt0 + (r >> 6)) * DJ + k8);
            const float4* pp = (const float4*)(predp + (size_t)(bu0 + (r & 63)) * DJ + k8);
            float4 e0 = pe[0], e1 = pe[1];
            float4 p0 = pp[0], p1 = pp[1];
            uint4 v;
            v.x = (u32)f2bf(fast_tanh(e0.x + p0.x)) | ((u32)f2bf(fast_tanh(e0.y + p0.y)) << 16);
            v.y = (u32)f2bf(fast_tanh(e0.z + p0.z)) | ((u32)f2bf(fast_tanh(e0.w + p0.w)) << 16);
            v.z = (u32)f2bf(fast_tanh(e1.x + p1.x)) | ((u32)f2bf(fast_tanh(e1.y + p1.y)) << 16);
            v.w = (u32)f2bf(fast_tanh(e1.z + p1.z)) | ((u32)f2bf(fast_tanh(e1.w + p1.w)) << 16);
            *(uint4*)(As + r * 64 + ((c ^ (r & 7)) * 8)) = v;   // swizzled ds_write_b128
        }
        __syncthreads();

        bf16x8 af[4], bfr[4];
        // K-half s=0
#pragma unroll
        for (int i = 0; i < 4; i++)
            af[i] = *(const bf16x8*)(As + abase + i * 16 * 64 + c0);
#pragma unroll
        for (int j = 0; j < 4; j++)
            bfr[j] = *(const bf16x8*)(Bs + bbase + j * 16 * 64 + c0);
#pragma unroll
        for (int i = 0; i < 4; i++)
#pragma unroll
            for (int j = 0; j < 4; j++)
                acc[i][j] = __builtin_amdgcn_mfma_f32_16x16x32_bf16(af[i], bfr[j], acc[i][j], 0, 0, 0);
        // K-half s=1
#pragma unroll
        for (int i = 0; i < 4; i++)
            af[i] = *(const bf16x8*)(As + abase + i * 16 * 64 + c1);
#pragma unroll
        for (int j = 0; j < 4; j++)
            bfr[j] = *(const bf16x8*)(Bs + bbase + j * 16 * 64 + c1);
#pragma unroll
        for (int i = 0; i < 4; i++)
#pragma unroll
            for (int j = 0; j < 4; j++)
                acc[i][j] = __builtin_amdgcn_mfma_f32_16x16x32_bf16(af[i], bfr[j], acc[i][j], 0, 0, 0);

        __syncthreads();
    }

#pragma unroll
    for (int j = 0; j < 4; j++) {
        int gc = n0 + wn * 64 + j * 16 + lm;
        float bo = b_out[gc];
#pragma unroll
        for (int i = 0; i < 4; i++) {
            int gr = row0 + wm * 64 + i * 16 + quad * 4;
#pragma unroll
            for (int r = 0; r < 4; r++) {
                float v = acc[i][j][r] + bo;
                v = fminf(fmaxf(v, -15.0f), 15.0f);
                out[(size_t)(gr + r) * VOCAB + gc] = v;
            }
        }
    }
}

extern "C" void kernel_launch(void* const* d_in, const int* in_sizes, int n_in,
                              void* d_out, int out_size, void* d_ws, size_t ws_size,
                              hipStream_t stream) {
    const float* enc    = (const float*)d_in[0];
    const float* pred   = (const float*)d_in[1];
    const float* W_enc  = (const float*)d_in[2];
    const float* b_enc  = (const float*)d_in[3];
    const float* W_pred = (const float*)d_in[4];
    const float* b_pred = (const float*)d_in[5];
    const float* W_out  = (const float*)d_in[6];
    const float* b_out  = (const float*)d_in[7];
    float* out = (float*)d_out;

    float* enc_proj  = (float*)d_ws;                     // 1024*640 f32
    float* pred_proj = enc_proj + 1024 * DJ;             // 256*640 f32
    u16*   Wt        = (u16*)(pred_proj + 256 * DJ);     // 1024*640 bf16
    // need = (1024+256)*640*4 + 1024*640*2 ≈ 4.6 MB — strictly less than the previous
    // layout (which included an 80 MB Abuf and ran), so ws_size is guaranteed sufficient.

    convert_wout<<<dim3(32, 20), dim3(256), 0, stream>>>(W_out, Wt);
    proj_kernel<512><<<dim3(256, 5), dim3(128), 0, stream>>>(enc, W_enc, b_enc, enc_proj);
    proj_kernel<640><<<dim3(64, 5), dim3(128), 0, stream>>>(pred, W_pred, b_pred, pred_proj);
    fused_gemm<<<dim3(4096), dim3(256), 0, stream>>>(enc_proj, pred_proj, Wt, b_out, out);
}

// Round 12
// 471.248 us; speedup vs baseline: 1.2636x; 1.2636x over previous
//
#include <hip/hip_runtime.h>

typedef unsigned short u16;
typedef unsigned int u32;
typedef __bf16 bf16x8 __attribute__((ext_vector_type(8)));
typedef float f32x4 __attribute__((ext_vector_type(4)));

#define T_DIM 256
#define U_DIM 64
#define DJ 640
#define VOCAB 1024

typedef __attribute__((address_space(3))) u32 lds_u32;
typedef const __attribute__((address_space(1))) u32 glb_u32;

__device__ __forceinline__ u16 f2bf(float f) {
    u32 x = __float_as_uint(f);
    x += 0x7fffu + ((x >> 16) & 1u);
    return (u16)(x >> 16);
}

__device__ __forceinline__ float fast_tanh(float x) {
    float e = __expf(2.0f * x);
    return 1.0f - 2.0f / (e + 1.0f);
}

// W_out (640x1024 fp32) -> Wt (1024x640 bf16, [n][k]) via 32x32 LDS tile transpose.
__global__ __launch_bounds__(256) void convert_wout(const float* __restrict__ W,
                                                    u16* __restrict__ Wt) {
    __shared__ float tile[32][33];
    int tx = threadIdx.x & 31, ty = threadIdx.x >> 5;
    int n0 = blockIdx.x * 32, k0 = blockIdx.y * 32;
#pragma unroll
    for (int j = 0; j < 4; j++)
        tile[ty + j * 8][tx] = W[(size_t)(k0 + ty + j * 8) * VOCAB + n0 + tx];
    __syncthreads();
#pragma unroll
    for (int j = 0; j < 4; j++)
        Wt[(size_t)(n0 + ty + j * 8) * DJ + k0 + tx] = f2bf(tile[tx][ty + j * 8]);
}

// out[r,j] = bias[j] + sum_k X[r,k]*W[k,j]; 4 rows x 128 cols per block, K compile-time
template <int K>
__global__ __launch_bounds__(128) void proj_kernel(const float* __restrict__ X,
                                                   const float* __restrict__ W,
                                                   const float* __restrict__ bias,
                                                   float* __restrict__ out) {
    __shared__ float xs[4][K];
    int r0 = blockIdx.x * 4;
    int jj = blockIdx.y * 128 + threadIdx.x;
    for (int idx = threadIdx.x; idx < 4 * K; idx += 128) {
        int r = idx / K, k = idx - r * K;
        xs[r][k] = X[(size_t)(r0 + r) * K + k];
    }
    __syncthreads();
    float b = bias[jj];
    float a0 = b, a1 = b, a2 = b, a3 = b;
#pragma unroll 8
    for (int k = 0; k < K; k++) {
        float w = W[(size_t)k * DJ + jj];
        a0 = fmaf(xs[0][k], w, a0);
        a1 = fmaf(xs[1][k], w, a1);
        a2 = fmaf(xs[2][k], w, a2);
        a3 = fmaf(xs[3][k], w, a3);
    }
    out[(size_t)(r0 + 0) * DJ + jj] = a0;
    out[(size_t)(r0 + 1) * DJ + jj] = a1;
    out[(size_t)(r0 + 2) * DJ + jj] = a2;
    out[(size_t)(r0 + 3) * DJ + jj] = a3;
}

// A[m][k] = bf16(tanh(encp[b,t,k] + predp[b,u,k])), m = ((b*T+t)*U+u), 8 elems/thread
__global__ __launch_bounds__(256) void tanh_kernel(const float* __restrict__ encp,
                                                   const float* __restrict__ predp,
                                                   u16* __restrict__ A) {
    int id = blockIdx.x * 256 + threadIdx.x;     // 65536*80 ids
    int m = id / 80;
    int c = id - m * 80;
    int koff = c * 8;
    int b = m >> 14, t = (m >> 6) & 255, u = m & 63;
    const float4* pe = (const float4*)(encp + (size_t)(b * T_DIM + t) * DJ + koff);
    const float4* pp = (const float4*)(predp + (size_t)(b * U_DIM + u) * DJ + koff);
    float4 e0 = pe[0], e1 = pe[1];
    float4 p0 = pp[0], p1 = pp[1];
    uint4 v;
    v.x = (u32)f2bf(fast_tanh(e0.x + p0.x)) | ((u32)f2bf(fast_tanh(e0.y + p0.y)) << 16);
    v.y = (u32)f2bf(fast_tanh(e0.z + p0.z)) | ((u32)f2bf(fast_tanh(e0.w + p0.w)) << 16);
    v.z = (u32)f2bf(fast_tanh(e1.x + p1.x)) | ((u32)f2bf(fast_tanh(e1.y + p1.y)) << 16);
    v.w = (u32)f2bf(fast_tanh(e1.z + p1.z)) | ((u32)f2bf(fast_tanh(e1.w + p1.w)) << 16);
    *(uint4*)(A + (size_t)id * 8) = v;
}

// bf16 GEMM: C[65536x1024] = A[65536x640] * Wt[1024x640]^T + bias, clamp.
// 128x128 tile, 256 threads, BK=64, both-sides XOR LDS swizzle (rule #21),
// bijective XCD-aware block swizzle (T1). Main loop identical to the R4/R5-verified kernel.
// Coalesced epilogue: C-tile staged through LDS (reusing As/Bs, 2x 64-row rounds),
// stored as float4 (512B contiguous per wave-row) instead of scattered 64B dword segments.
__global__ __launch_bounds__(256) void gemm_kernel(const u16* __restrict__ A,
                                                   const u16* __restrict__ Wt,
                                                   const float* __restrict__ b_out,
                                                   float* __restrict__ out) {
    __shared__ u16 smem[2 * 128 * 64];   // As (16KB) + Bs (16KB); aliased as f32[64][128] in epilogue
    u16* As = smem;
    u16* Bs = smem + 128 * 64;

    // XCD swizzle: 4096 blocks, 8 XCDs, 512 per chunk (4096 % 8 == 0 -> bijective).
    int bid = blockIdx.x;
    int swz = (bid & 7) * 512 + (bid >> 3);
    int ntile = swz & 7;
    int mtile = swz >> 3;
    int row0 = mtile * 128;
    int n0 = ntile * 128;

    int tid = threadIdx.x;
    int lane = tid & 63;
    int wave = tid >> 6;
    int wm = wave & 1;
    int wn = wave >> 1;
    int lm = lane & 15;
    int quad = lane >> 4;

    // staging: inst i covers rows i*32 + wave*8 + (lane>>3), 8 lanes per 128B row.
    int rS = wave * 8 + (lane >> 3);
    int kSwz = ((lane ^ (lane >> 3)) & 7) * 8;          // pre-swizzled global k-chunk
    const u16* gA = A + (size_t)(row0 + rS) * DJ + kSwz;
    const u16* gB = Wt + (size_t)(n0 + rS) * DJ + kSwz;
    u16* lA = As + wave * 8 * 64;    // wave-uniform; HW adds lane*16B (linear dest)
    u16* lB = Bs + wave * 8 * 64;

    // read side: logical chunk (s*4+quad) lives at slot (s*4+quad) ^ (row&7), row&7 == lm&7
    int abase = (wm * 64 + lm) * 64;
    int bbase = (wn * 64 + lm) * 64;
    int c0 = ((quad ^ (lm & 7))) * 8;                   // s = 0
    int c1 = (((quad ^ 4) ^ (lm & 7))) * 8;             // s = 1

    f32x4 acc[4][4];
#pragma unroll
    for (int i = 0; i < 4; i++)
#pragma unroll
        for (int j = 0; j < 4; j++) {
            acc[i][j][0] = 0.f; acc[i][j][1] = 0.f;
            acc[i][j][2] = 0.f; acc[i][j][3] = 0.f;
        }

    for (int k0 = 0; k0 < DJ; k0 += 64) {
#pragma unroll
        for (int i = 0; i < 4; i++) {
            __builtin_amdgcn_global_load_lds((glb_u32*)(gA + (size_t)i * 32 * DJ + k0),
                                             (lds_u32*)(lA + i * 32 * 64), 16, 0, 0);
            __builtin_amdgcn_global_load_lds((glb_u32*)(gB + (size_t)i * 32 * DJ + k0),
                                             (lds_u32*)(lB + i * 32 * 64), 16, 0, 0);
        }
        __syncthreads();

        bf16x8 af[4], bfr[4];
        // K-half s=0
#pragma unroll
        for (int i = 0; i < 4; i++)
            af[i] = *(const bf16x8*)(As + abase + i * 16 * 64 + c0);
#pragma unroll
        for (int j = 0; j < 4; j++)
            bfr[j] = *(const bf16x8*)(Bs + bbase + j * 16 * 64 + c0);
#pragma unroll
        for (int i = 0; i < 4; i++)
#pragma unroll
            for (int j = 0; j < 4; j++)
                acc[i][j] = __builtin_amdgcn_mfma_f32_16x16x32_bf16(af[i], bfr[j], acc[i][j], 0, 0, 0);
        // K-half s=1
#pragma unroll
        for (int i = 0; i < 4; i++)
            af[i] = *(const bf16x8*)(As + abase + i * 16 * 64 + c1);
#pragma unroll
        for (int j = 0; j < 4; j++)
            bfr[j] = *(const bf16x8*)(Bs + bbase + j * 16 * 64 + c1);
#pragma unroll
        for (int i = 0; i < 4; i++)
#pragma unroll
            for (int j = 0; j < 4; j++)
                acc[i][j] = __builtin_amdgcn_mfma_f32_16x16x32_bf16(af[i], bfr[j], acc[i][j], 0, 0, 0);

        __syncthreads();
    }

    // ---- coalesced epilogue: 2 rounds of 64 tile-rows staged through LDS ----
    // round rnd covers tile rows {wm*64 + rnd*32 + 0..31} for both wm (64 rows total).
    // LDS layout f32 cs[64][128]: lrow = wm*32 + ii*16 + quad*4 + r, lcol = wn*64 + j*16 + lm.
    float* cs = (float*)smem;            // 32 KB = 64*128 f32, exact fit
#pragma unroll
    for (int rnd = 0; rnd < 2; rnd++) {
        __syncthreads();                 // previous smem use (K-loop / prior round reads) done
#pragma unroll
        for (int ii = 0; ii < 2; ii++) {
            int i = rnd * 2 + ii;
            int lrow = wm * 32 + ii * 16 + quad * 4;
#pragma unroll
            for (int j = 0; j < 4; j++) {
                int lcol = wn * 64 + j * 16 + lm;
#pragma unroll
                for (int r = 0; r < 4; r++)
                    cs[(lrow + r) * 128 + lcol] = acc[i][j][r];
            }
        }
        __syncthreads();
        // read back row-major: 64 rows x 32 float4-groups = 2048 groups, 8 per thread
#pragma unroll
        for (int t = 0; t < 8; t++) {
            int g = tid + t * 256;
            int lrow2 = g >> 5;          // 0..63
            int gc4 = (g & 31) * 4;      // col offset 0..124
            f32x4 v = *(const f32x4*)(cs + lrow2 * 128 + gc4);
            f32x4 b4 = *(const f32x4*)(b_out + n0 + gc4);
            int grow = row0 + (lrow2 >> 5) * 64 + rnd * 32 + (lrow2 & 31);
#pragma unroll
            for (int cc = 0; cc < 4; cc++) {
                float x = v[cc] + b4[cc];
                v[cc] = fminf(fmaxf(x, -15.0f), 15.0f);
            }
            *(f32x4*)(out + (size_t)grow * VOCAB + n0 + gc4) = v;
        }
    }
}

// ---------------- fallback (round-1 fused kernel) if ws too small ----------------
#define LDA 40
__global__ __launch_bounds__(256) void joint_fused(const float* __restrict__ encp,
                                                   const float* __restrict__ predp,
                                                   const u16* __restrict__ Wt,
                                                   const float* __restrict__ b_out,
                                                   float* __restrict__ out) {
    __shared__ u16 As[128 * LDA];
    __shared__ u16 Bs[128 * LDA];
    int ntile = blockIdx.x & 7;
    int mtile = blockIdx.x >> 3;
    int row0 = mtile * 128;
    int bidx = row0 >> 14;
    int t0 = (row0 & 16383) >> 6;
    int n0 = ntile * 128;
    int tid = threadIdx.x, lane = tid & 63, wave = tid >> 6;
    int wm = wave & 1, wn = wave >> 1, lm = lane & 15, quad = lane >> 4;
    int am = tid >> 1, ak = (tid & 1) << 4;
    const float* encA = encp + (size_t)(bidx * T_DIM + t0 + (am >> 6)) * DJ + ak;
    const float* predA = predp + (size_t)(bidx * U_DIM + (am & 63)) * DJ + ak;
    u16* Asw = As + am * LDA + ak;
    int bn = tid >> 1, bk = (tid & 1) << 4;
    const u16* WtB = Wt + (size_t)(n0 + bn) * DJ + bk;
    u16* Bsw = Bs + bn * LDA + bk;
    f32x4 acc[4][4];
#pragma unroll
    for (int i = 0; i < 4; i++)
#pragma unroll
        for (int j = 0; j < 4; j++) {
            acc[i][j][0] = 0.f; acc[i][j][1] = 0.f; acc[i][j][2] = 0.f; acc[i][j][3] = 0.f;
        }
    for (int k0 = 0; k0 < DJ; k0 += 32) {
        const float4* pe = (const float4*)(encA + k0);
        const float4* pp = (const float4*)(predA + k0);
#pragma unroll
        for (int i = 0; i < 4; i++) {
            float4 e = pe[i]; float4 p = pp[i];
            uint2 v;
            v.x = (u32)f2bf(fast_tanh(e.x + p.x)) | ((u32)f2bf(fast_tanh(e.y + p.y)) << 16);
            v.y = (u32)f2bf(fast_tanh(e.z + p.z)) | ((u32)f2bf(fast_tanh(e.w + p.w)) << 16);
            *(uint2*)(Asw + i * 4) = v;
        }
        const u16* src = WtB + k0;
        uint4 w0 = *(const uint4*)src;
        uint4 w1 = *(const uint4*)(src + 8);
        *(uint4*)Bsw = w0;
        *(uint4*)(Bsw + 8) = w1;
        __syncthreads();
        bf16x8 af[4], bfr[4];
#pragma unroll
        for (int i = 0; i < 4; i++)
            af[i] = *(const bf16x8*)(As + (wm * 64 + i * 16 + lm) * LDA + quad * 8);
#pragma unroll
        for (int j = 0; j < 4; j++)
            bfr[j] = *(const bf16x8*)(Bs + (wn * 64 + j * 16 + lm) * LDA + quad * 8);
#pragma unroll
        for (int i = 0; i < 4; i++)
#pragma unroll
            for (int j = 0; j < 4; j++)
                acc[i][j] = __builtin_amdgcn_mfma_f32_16x16x32_bf16(af[i], bfr[j], acc[i][j], 0, 0, 0);
        __syncthreads();
    }
#pragma unroll
    for (int j = 0; j < 4; j++) {
        int gc = n0 + wn * 64 + j * 16 + lm;
        float bo = b_out[gc];
#pragma unroll
        for (int i = 0; i < 4; i++) {
            int gr = row0 + wm * 64 + i * 16 + quad * 4;
#pragma unroll
            for (int r = 0; r < 4; r++) {
                float v = acc[i][j][r] + bo;
                v = fminf(fmaxf(v, -15.0f), 15.0f);
                out[(size_t)(gr + r) * VOCAB + gc] = v;
            }
        }
    }
}

extern "C" void kernel_launch(void* const* d_in, const int* in_sizes, int n_in,
                              void* d_out, int out_size, void* d_ws, size_t ws_size,
                              hipStream_t stream) {
    const float* enc    = (const float*)d_in[0];
    const float* pred   = (const float*)d_in[1];
    const float* W_enc  = (const float*)d_in[2];
    const float* b_enc  = (const float*)d_in[3];
    const float* W_pred = (const float*)d_in[4];
    const float* b_pred = (const float*)d_in[5];
    const float* W_out  = (const float*)d_in[6];
    const float* b_out  = (const float*)d_in[7];
    float* out = (float*)d_out;

    float* enc_proj  = (float*)d_ws;                     // 1024*640 f32
    float* pred_proj = enc_proj + 1024 * DJ;             // 256*640 f32
    u16*   Wt        = (u16*)(pred_proj + 256 * DJ);     // 1024*640 bf16
    u16*   Abuf      = Wt + 1024 * DJ;                   // 65536*640 bf16

    size_t need = (size_t)(1024 + 256) * DJ * 4 + (size_t)1024 * DJ * 2
                + (size_t)65536 * DJ * 2;

    convert_wout<<<dim3(32, 20), dim3(256), 0, stream>>>(W_out, Wt);
    proj_kernel<512><<<dim3(256, 5), dim3(128), 0, stream>>>(enc, W_enc, b_enc, enc_proj);
    proj_kernel<640><<<dim3(64, 5), dim3(128), 0, stream>>>(pred, W_pred, b_pred, pred_proj);

    if (ws_size >= need) {
        tanh_kernel<<<dim3(65536 * 80 / 256), dim3(256), 0, stream>>>(enc_proj, pred_proj, Abuf);
        gemm_kernel<<<dim3(4096), dim3(256), 0, stream>>>(Abuf, Wt, b_out, out);
    } else {
        joint_fused<<<dim3(4096), dim3(256), 0, stream>>>(enc_proj, pred_proj, Wt, b_out, out);
    }
}

// Round 13
// 432.672 us; speedup vs baseline: 1.3763x; 1.0892x over previous
//
#include <hip/hip_runtime.h>

typedef unsigned short u16;
typedef unsigned int u32;
typedef __bf16 bf16x8 __attribute__((ext_vector_type(8)));
typedef float f32x4 __attribute__((ext_vector_type(4)));

#define T_DIM 256
#define U_DIM 64
#define DJ 640
#define VOCAB 1024

typedef __attribute__((address_space(3))) u32 lds_u32;
typedef const __attribute__((address_space(1))) u32 glb_u32;

__device__ __forceinline__ u16 f2bf(float f) {
    u32 x = __float_as_uint(f);
    x += 0x7fffu + ((x >> 16) & 1u);
    return (u16)(x >> 16);
}

__device__ __forceinline__ float fast_tanh(float x) {
    float e = __expf(2.0f * x);
    return 1.0f - 2.0f / (e + 1.0f);
}

// Fused prep (one dispatch, 128 threads/block, block-uniform branch):
//   blocks 0..1279    : enc projection  (was proj_kernel<512>, grid 256x5)
//   blocks 1280..1599 : pred projection (was proj_kernel<640>, grid 64x5)
//   blocks 1600..2239 : W_out -> Wt bf16 transpose (was convert_wout, grid 32x20)
__global__ __launch_bounds__(128) void prep_kernel(const float* __restrict__ enc,
                                                   const float* __restrict__ W_enc,
                                                   const float* __restrict__ b_enc,
                                                   const float* __restrict__ pred,
                                                   const float* __restrict__ W_pred,
                                                   const float* __restrict__ b_pred,
                                                   const float* __restrict__ W_out,
                                                   float* __restrict__ enc_proj,
                                                   float* __restrict__ pred_proj,
                                                   u16* __restrict__ Wt) {
    __shared__ float smem[4 * 640];          // proj: xs[4][K] (<=10240B); convert: tile[32][33] (4224B)
    int b = blockIdx.x;
    int tid = threadIdx.x;

    if (b < 1600) {
        const float* X; const float* W; const float* bias; float* out; int K, r0, jj;
        if (b < 1280) {                      // enc proj: bx = b&255, by = b>>8  (5*256 blocks)
            X = enc;  W = W_enc;  bias = b_enc;  out = enc_proj;  K = 512;
            r0 = (b & 255) * 4;  jj = (b >> 8) * 128 + tid;
        } else {                             // pred proj: b2 = b-1280; bx = b2&63, by = b2>>6
            int b2 = b - 1280;
            X = pred; W = W_pred; bias = b_pred; out = pred_proj; K = 640;
            r0 = (b2 & 63) * 4;  jj = (b2 >> 6) * 128 + tid;
        }
        float* xs = smem;                    // xs[r*K + k]
        for (int idx = tid; idx < 4 * K; idx += 128) {
            int r = idx / K, k = idx - r * K;
            xs[r * K + k] = X[(size_t)(r0 + r) * K + k];
        }
        __syncthreads();
        float bb = bias[jj];
        float a0 = bb, a1 = bb, a2 = bb, a3 = bb;
#pragma unroll 8
        for (int k = 0; k < K; k++) {
            float w = W[(size_t)k * DJ + jj];
            a0 = fmaf(xs[k], w, a0);
            a1 = fmaf(xs[K + k], w, a1);
            a2 = fmaf(xs[2 * K + k], w, a2);
            a3 = fmaf(xs[3 * K + k], w, a3);
        }
        out[(size_t)(r0 + 0) * DJ + jj] = a0;
        out[(size_t)(r0 + 1) * DJ + jj] = a1;
        out[(size_t)(r0 + 2) * DJ + jj] = a2;
        out[(size_t)(r0 + 3) * DJ + jj] = a3;
    } else {                                 // convert: b3 = b-1600; n0 = (b3&31)*32, k0 = (b3>>5)*32
        float (*tile)[33] = (float(*)[33])smem;
        int b3 = b - 1600;
        int n0 = (b3 & 31) * 32, k0 = (b3 >> 5) * 32;
        int tx = tid & 31, ty4 = tid >> 5;   // ty4 in 0..3, rows ty4 + j*4 cover 0..31
#pragma unroll
        for (int j = 0; j < 8; j++)
            tile[ty4 + j * 4][tx] = W_out[(size_t)(k0 + ty4 + j * 4) * VOCAB + n0 + tx];
        __syncthreads();
#pragma unroll
        for (int j = 0; j < 8; j++)
            Wt[(size_t)(n0 + ty4 + j * 4) * DJ + k0 + tx] = f2bf(tile[tx][ty4 + j * 4]);
    }
}

// A[m][k] = bf16(tanh(encp[b,t,k] + predp[b,u,k])), m = ((b*T+t)*U+u), 8 elems/thread
__global__ __launch_bounds__(256) void tanh_kernel(const float* __restrict__ encp,
                                                   const float* __restrict__ predp,
                                                   u16* __restrict__ A) {
    int id = blockIdx.x * 256 + threadIdx.x;     // 65536*80 ids
    int m = id / 80;
    int c = id - m * 80;
    int koff = c * 8;
    int b = m >> 14, t = (m >> 6) & 255, u = m & 63;
    const float4* pe = (const float4*)(encp + (size_t)(b * T_DIM + t) * DJ + koff);
    const float4* pp = (const float4*)(predp + (size_t)(b * U_DIM + u) * DJ + koff);
    float4 e0 = pe[0], e1 = pe[1];
    float4 p0 = pp[0], p1 = pp[1];
    uint4 v;
    v.x = (u32)f2bf(fast_tanh(e0.x + p0.x)) | ((u32)f2bf(fast_tanh(e0.y + p0.y)) << 16);
    v.y = (u32)f2bf(fast_tanh(e0.z + p0.z)) | ((u32)f2bf(fast_tanh(e0.w + p0.w)) << 16);
    v.z = (u32)f2bf(fast_tanh(e1.x + p1.x)) | ((u32)f2bf(fast_tanh(e1.y + p1.y)) << 16);
    v.w = (u32)f2bf(fast_tanh(e1.z + p1.z)) | ((u32)f2bf(fast_tanh(e1.w + p1.w)) << 16);
    *(uint4*)(A + (size_t)id * 8) = v;
}

// bf16 GEMM: C[65536x1024] = A[65536x640] * Wt[1024x640]^T + bias, clamp.
// 128x128 tile, 256 threads, BK=64, both-sides XOR LDS swizzle (rule #21),
// bijective XCD-aware block swizzle (T1). Main loop identical to the R4/R5-verified kernel.
// Coalesced epilogue (R12-verified): C staged through LDS, stored as contiguous float4 rows.
__global__ __launch_bounds__(256) void gemm_kernel(const u16* __restrict__ A,
                                                   const u16* __restrict__ Wt,
                                                   const float* __restrict__ b_out,
                                                   float* __restrict__ out) {
    __shared__ u16 smem[2 * 128 * 64];   // As (16KB) + Bs (16KB); aliased as f32[64][128] in epilogue
    u16* As = smem;
    u16* Bs = smem + 128 * 64;

    // XCD swizzle: 4096 blocks, 8 XCDs, 512 per chunk (4096 % 8 == 0 -> bijective).
    int bid = blockIdx.x;
    int swz = (bid & 7) * 512 + (bid >> 3);
    int ntile = swz & 7;
    int mtile = swz >> 3;
    int row0 = mtile * 128;
    int n0 = ntile * 128;

    int tid = threadIdx.x;
    int lane = tid & 63;
    int wave = tid >> 6;
    int wm = wave & 1;
    int wn = wave >> 1;
    int lm = lane & 15;
    int quad = lane >> 4;

    // staging: inst i covers rows i*32 + wave*8 + (lane>>3), 8 lanes per 128B row.
    int rS = wave * 8 + (lane >> 3);
    int kSwz = ((lane ^ (lane >> 3)) & 7) * 8;          // pre-swizzled global k-chunk
    const u16* gA = A + (size_t)(row0 + rS) * DJ + kSwz;
    const u16* gB = Wt + (size_t)(n0 + rS) * DJ + kSwz;
    u16* lA = As + wave * 8 * 64;    // wave-uniform; HW adds lane*16B (linear dest)
    u16* lB = Bs + wave * 8 * 64;

    // read side: logical chunk (s*4+quad) lives at slot (s*4+quad) ^ (row&7), row&7 == lm&7
    int abase = (wm * 64 + lm) * 64;
    int bbase = (wn * 64 + lm) * 64;
    int c0 = ((quad ^ (lm & 7))) * 8;                   // s = 0
    int c1 = (((quad ^ 4) ^ (lm & 7))) * 8;             // s = 1

    f32x4 acc[4][4];
#pragma unroll
    for (int i = 0; i < 4; i++)
#pragma unroll
        for (int j = 0; j < 4; j++) {
            acc[i][j][0] = 0.f; acc[i][j][1] = 0.f;
            acc[i][j][2] = 0.f; acc[i][j][3] = 0.f;
        }

    for (int k0 = 0; k0 < DJ; k0 += 64) {
#pragma unroll
        for (int i = 0; i < 4; i++) {
            __builtin_amdgcn_global_load_lds((glb_u32*)(gA + (size_t)i * 32 * DJ + k0),
                                             (lds_u32*)(lA + i * 32 * 64), 16, 0, 0);
            __builtin_amdgcn_global_load_lds((glb_u32*)(gB + (size_t)i * 32 * DJ + k0),
                                             (lds_u32*)(lB + i * 32 * 64), 16, 0, 0);
        }
        __syncthreads();

        bf16x8 af[4], bfr[4];
        // K-half s=0
#pragma unroll
        for (int i = 0; i < 4; i++)
            af[i] = *(const bf16x8*)(As + abase + i * 16 * 64 + c0);
#pragma unroll
        for (int j = 0; j < 4; j++)
            bfr[j] = *(const bf16x8*)(Bs + bbase + j * 16 * 64 + c0);
#pragma unroll
        for (int i = 0; i < 4; i++)
#pragma unroll
            for (int j = 0; j < 4; j++)
                acc[i][j] = __builtin_amdgcn_mfma_f32_16x16x32_bf16(af[i], bfr[j], acc[i][j], 0, 0, 0);
        // K-half s=1
#pragma unroll
        for (int i = 0; i < 4; i++)
            af[i] = *(const bf16x8*)(As + abase + i * 16 * 64 + c1);
#pragma unroll
        for (int j = 0; j < 4; j++)
            bfr[j] = *(const bf16x8*)(Bs + bbase + j * 16 * 64 + c1);
#pragma unroll
        for (int i = 0; i < 4; i++)
#pragma unroll
            for (int j = 0; j < 4; j++)
                acc[i][j] = __builtin_amdgcn_mfma_f32_16x16x32_bf16(af[i], bfr[j], acc[i][j], 0, 0, 0);

        __syncthreads();
    }

    // ---- coalesced epilogue: 2 rounds of 64 tile-rows staged through LDS ----
    float* cs = (float*)smem;            // 32 KB = 64*128 f32, exact fit
#pragma unroll
    for (int rnd = 0; rnd < 2; rnd++) {
        __syncthreads();
#pragma unroll
        for (int ii = 0; ii < 2; ii++) {
            int i = rnd * 2 + ii;
            int lrow = wm * 32 + ii * 16 + quad * 4;
#pragma unroll
            for (int j = 0; j < 4; j++) {
                int lcol = wn * 64 + j * 16 + lm;
#pragma unroll
                for (int r = 0; r < 4; r++)
                    cs[(lrow + r) * 128 + lcol] = acc[i][j][r];
            }
        }
        __syncthreads();
#pragma unroll
        for (int t = 0; t < 8; t++) {
            int g = tid + t * 256;
            int lrow2 = g >> 5;          // 0..63
            int gc4 = (g & 31) * 4;      // col offset 0..124
            f32x4 v = *(const f32x4*)(cs + lrow2 * 128 + gc4);
            f32x4 b4 = *(const f32x4*)(b_out + n0 + gc4);
            int grow = row0 + (lrow2 >> 5) * 64 + rnd * 32 + (lrow2 & 31);
#pragma unroll
            for (int cc = 0; cc < 4; cc++) {
                float x = v[cc] + b4[cc];
                v[cc] = fminf(fmaxf(x, -15.0f), 15.0f);
            }
            *(f32x4*)(out + (size_t)grow * VOCAB + n0 + gc4) = v;
        }
    }
}

// ---------------- fallback (round-1 fused kernel) if ws too small ----------------
#define LDA 40
__global__ __launch_bounds__(256) void joint_fused(const float* __restrict__ encp,
                                                   const float* __restrict__ predp,
                                                   const u16* __restrict__ Wt,
                                                   const float* __restrict__ b_out,
                                                   float* __restrict__ out) {
    __shared__ u16 As[128 * LDA];
    __shared__ u16 Bs[128 * LDA];
    int ntile = blockIdx.x & 7;
    int mtile = blockIdx.x >> 3;
    int row0 = mtile * 128;
    int bidx = row0 >> 14;
    int t0 = (row0 & 16383) >> 6;
    int n0 = ntile * 128;
    int tid = threadIdx.x, lane = tid & 63, wave = tid >> 6;
    int wm = wave & 1, wn = wave >> 1, lm = lane & 15, quad = lane >> 4;
    int am = tid >> 1, ak = (tid & 1) << 4;
    const float* encA = encp + (size_t)(bidx * T_DIM + t0 + (am >> 6)) * DJ + ak;
    const float* predA = predp + (size_t)(bidx * U_DIM + (am & 63)) * DJ + ak;
    u16* Asw = As + am * LDA + ak;
    int bn = tid >> 1, bk = (tid & 1) << 4;
    const u16* WtB = Wt + (size_t)(n0 + bn) * DJ + bk;
    u16* Bsw = Bs + bn * LDA + bk;
    f32x4 acc[4][4];
#pragma unroll
    for (int i = 0; i < 4; i++)
#pragma unroll
        for (int j = 0; j < 4; j++) {
            acc[i][j][0] = 0.f; acc[i][j][1] = 0.f; acc[i][j][2] = 0.f; acc[i][j][3] = 0.f;
        }
    for (int k0 = 0; k0 < DJ; k0 += 32) {
        const float4* pe = (const float4*)(encA + k0);
        const float4* pp = (const float4*)(predA + k0);
#pragma unroll
        for (int i = 0; i < 4; i++) {
            float4 e = pe[i]; float4 p = pp[i];
            uint2 v;
            v.x = (u32)f2bf(fast_tanh(e.x + p.x)) | ((u32)f2bf(fast_tanh(e.y + p.y)) << 16);
            v.y = (u32)f2bf(fast_tanh(e.z + p.z)) | ((u32)f2bf(fast_tanh(e.w + p.w)) << 16);
            *(uint2*)(Asw + i * 4) = v;
        }
        const u16* src = WtB + k0;
        uint4 w0 = *(const uint4*)src;
        uint4 w1 = *(const uint4*)(src + 8);
        *(uint4*)Bsw = w0;
        *(uint4*)(Bsw + 8) = w1;
        __syncthreads();
        bf16x8 af[4], bfr[4];
#pragma unroll
        for (int i = 0; i < 4; i++)
            af[i] = *(const bf16x8*)(As + (wm * 64 + i * 16 + lm) * LDA + quad * 8);
#pragma unroll
        for (int j = 0; j < 4; j++)
            bfr[j] = *(const bf16x8*)(Bs + (wn * 64 + j * 16 + lm) * LDA + quad * 8);
#pragma unroll
        for (int i = 0; i < 4; i++)
#pragma unroll
            for (int j = 0; j < 4; j++)
                acc[i][j] = __builtin_amdgcn_mfma_f32_16x16x32_bf16(af[i], bfr[j], acc[i][j], 0, 0, 0);
        __syncthreads();
    }
#pragma unroll
    for (int j = 0; j < 4; j++) {
        int gc = n0 + wn * 64 + j * 16 + lm;
        float bo = b_out[gc];
#pragma unroll
        for (int i = 0; i < 4; i++) {
            int gr = row0 + wm * 64 + i * 16 + quad * 4;
#pragma unroll
            for (int r = 0; r < 4; r++) {
                float v = acc[i][j][r] + bo;
                v = fminf(fmaxf(v, -15.0f), 15.0f);
                out[(size_t)(gr + r) * VOCAB + gc] = v;
            }
        }
    }
}

extern "C" void kernel_launch(void* const* d_in, const int* in_sizes, int n_in,
                              void* d_out, int out_size, void* d_ws, size_t ws_size,
                              hipStream_t stream) {
    const float* enc    = (const float*)d_in[0];
    const float* pred   = (const float*)d_in[1];
    const float* W_enc  = (const float*)d_in[2];
    const float* b_enc  = (const float*)d_in[3];
    const float* W_pred = (const float*)d_in[4];
    const float* b_pred = (const float*)d_in[5];
    const float* W_out  = (const float*)d_in[6];
    const float* b_out  = (const float*)d_in[7];
    float* out = (float*)d_out;

    float* enc_proj  = (float*)d_ws;                     // 1024*640 f32
    float* pred_proj = enc_proj + 1024 * DJ;             // 256*640 f32
    u16*   Wt        = (u16*)(pred_proj + 256 * DJ);     // 1024*640 bf16
    u16*   Abuf      = Wt + 1024 * DJ;                   // 65536*640 bf16

    size_t need = (size_t)(1024 + 256) * DJ * 4 + (size_t)1024 * DJ * 2
                + (size_t)65536 * DJ * 2;

    prep_kernel<<<dim3(2240), dim3(128), 0, stream>>>(enc, W_enc, b_enc,
                                                      pred, W_pred, b_pred,
                                                      W_out, enc_proj, pred_proj, Wt);

    if (ws_size >= need) {
        tanh_kernel<<<dim3(65536 * 80 / 256), dim3(256), 0, stream>>>(enc_proj, pred_proj, Abuf);
        gemm_kernel<<<dim3(4096), dim3(256), 0, stream>>>(Abuf, Wt, b_out, out);
    } else {
        joint_fused<<<dim3(4096), dim3(256), 0, stream>>>(enc_proj, pred_proj, Wt, b_out, out);
    }
}